// Round 7
// baseline (136.934 us; speedup 1.0000x reference)
//
#include <hip/hip_runtime.h>
#include <hip/hip_bf16.h>

#define LN_EPS 1e-5f

typedef __attribute__((ext_vector_type(8))) short bf16x8;
typedef __attribute__((ext_vector_type(4))) float f32x4;

// ---- LDS arena (ushort units). Row stride S=136 (272 B, 16B-aligned;
// bank offset 68 dw == 4 mod 32 -> only free 2-way conflicts). ----
#define S 136
#define OFF_F  0      // T1t -> h1 (100 rows; row-spill reads land in A region: finite)
#define OFF_A  13600  // agg A (100 rows; 12 spill rows uninit -> discarded C cols)
#define OFF_S  28832  // W2p (20 rows + 12 uninit -> discarded C rows)
#define OFF_T2 33184  // T2t (rows 0-19 used; 20-31 uninit -> discarded C rows)
#define FLT    37536  // float scratch region
#define ARENA_U 39360 // 78720 B; x2 blocks = 157.4 KB <= 160 KB

// float-region indices
#define FB1  300  // b1 [100]
#define FB2  400  // b2 [20]
#define FG2  420
#define FBE2 440
#define FG3  460
#define FBE3 480
#define FWF1 500  // Wf1 [200]
#define FBF1 700  // bf1 [10] (+pad)
#define FWF2 712  // Wf2 [10] (+pad)
#define FBF2 724  // bf2 [1]  (+pad)
#define FV2  728  // V2 [32]
#define FV3  760  // V3 [32]
#define FZ2  792  // Z2 [20]
#define FZ3  812  // Z3 [20]
#define FHGP 832  // hg partials [4][20] (fully overwritten in P6 -> no init)

__device__ __forceinline__ unsigned short bf16rne(float x) {
    union { float f; unsigned u; } v; v.f = x;
    unsigned r = (v.u + 0x7FFFu + ((v.u >> 16) & 1u)) >> 16;
    return (unsigned short)r;
}

__device__ __forceinline__ unsigned pk2(float a, float b) {
    __hip_bfloat162 h = __float22bfloat162_rn(float2{a, b});
    unsigned r; __builtin_memcpy(&r, &h, 4); return r;
}

__device__ __forceinline__ void st4bf(unsigned short* p, const f32x4 v) {
    *(uint2*)p = make_uint2(pk2(v[0], v[1]), pk2(v[2], v[3]));
}

__device__ __forceinline__ bf16x8 pk8(const float4 a, const float4 b) {
    union { bf16x8 v; uint4 u; } r;
    r.u = make_uint4(pk2(a.x, a.y), pk2(a.z, a.w), pk2(b.x, b.y), pk2(b.z, b.w));
    return r.v;
}

// K=128 LDS pass, one m-tile row, NT n-tiles. A row-major [m][k]; B as Bt[n][k].
template<int NT>
__device__ __forceinline__ void gemm_row(const unsigned short* __restrict__ ar,
    int Abase, int Bbase, int mrow, int lm, int lq, f32x4 (&acc)[NT])
{
    #pragma unroll
    for (int ks = 0; ks < 4; ++ks) {
        const int k = ks * 32 + lq * 8;
        bf16x8 a = *(const bf16x8*)&ar[Abase + (mrow * 16 + lm) * S + k];
        #pragma unroll
        for (int n = 0; n < NT; ++n) {
            bf16x8 b = *(const bf16x8*)&ar[Bbase + (n * 16 + lm) * S + k];
            acc[n] = __builtin_amdgcn_mfma_f32_16x16x32_bf16(a, b, acc[n], 0, 0, 0);
        }
    }
}

// One block per graph, 512 threads (8 waves): 4 waves/SIMD at 2 blocks/CU.
// 5 barriers total: P0{stage+A-build+GEMM1+T1t+V/Z} | GEMM2 | h1 | GEMM3 | GEMM4 | tail.
__global__ __launch_bounds__(512, 4) void fused_net_v7(
    const float* __restrict__ feat, const int* __restrict__ edge_src,
    const float* __restrict__ self_feat, const float* __restrict__ x3d,
    const float* __restrict__ W1, const float* __restrict__ b1,
    const float* __restrict__ W2, const float* __restrict__ b2,
    const float* __restrict__ Wv2, const float* __restrict__ Wo2,
    const float* __restrict__ g2, const float* __restrict__ be2,
    const float* __restrict__ Wv3, const float* __restrict__ Wo3,
    const float* __restrict__ g3, const float* __restrict__ be3,
    const float* __restrict__ Wf1, const float* __restrict__ bf1,
    const float* __restrict__ Wf2, const float* __restrict__ bf2,
    float* __restrict__ out)
{
    __shared__ __align__(16) unsigned short ar[ARENA_U];
    float* fl = (float*)&ar[FLT];

    const int g    = blockIdx.x;
    const int tid  = threadIdx.x;
    const int w    = tid >> 6;      // 0..7
    const int lane = tid & 63;
    const int lm   = lane & 15;
    const int lq   = lane >> 4;

    // ---- param staging (waves 0-1 only; consumed after B1+) ----
    if (tid < 25)       *(float4*)&fl[FB1 + tid * 4]          = *(const float4*)&b1[tid * 4];
    else if (tid < 30)  *(float4*)&fl[FB2 + (tid - 25) * 4]   = *(const float4*)&b2[(tid - 25) * 4];
    else if (tid < 35)  *(float4*)&fl[FG2 + (tid - 30) * 4]   = *(const float4*)&g2[(tid - 30) * 4];
    else if (tid < 40)  *(float4*)&fl[FBE2 + (tid - 35) * 4]  = *(const float4*)&be2[(tid - 35) * 4];
    else if (tid < 45)  *(float4*)&fl[FG3 + (tid - 40) * 4]   = *(const float4*)&g3[(tid - 40) * 4];
    else if (tid < 50)  *(float4*)&fl[FBE3 + (tid - 45) * 4]  = *(const float4*)&be3[(tid - 45) * 4];
    else if (tid < 100) *(float4*)&fl[FWF1 + (tid - 50) * 4]  = *(const float4*)&Wf1[(tid - 50) * 4];
    else if (tid < 110) { const int j = tid - 100; fl[FBF1 + j] = bf1[j]; fl[FWF2 + j] = Wf2[j]; }
    else if (tid == 110) fl[FBF2] = bf2[0];

    // ================= P0: everything up to (and incl.) GEMM1 =================
    if (w < 7) {
        // --- feat -> A-fragments (GEMM1's only consumer of feat) ---
        bf16x8 afrag[4];
        {
            int am = w * 16 + lm; if (am > 99) am = 99;   // clamped rows -> discarded C rows
            const float* frow = feat + g * 10000 + am * 100;
            #pragma unroll
            for (int ks = 0; ks < 3; ++ks) {
                const int k = ks * 32 + lq * 8;
                afrag[ks] = pk8(*(const float4*)&frow[k], *(const float4*)&frow[k + 4]);
            }
            const float4 z4 = make_float4(0.f, 0.f, 0.f, 0.f);
            afrag[3] = (lq == 0) ? pk8(*(const float4*)&frow[96], z4) : pk8(z4, z4);
        }

        // --- staging (tid 0..447, stride 448) ---
        for (int i = tid; i < 500; i += 448) {            // W2 -> OFF_S (rows 0-19)
            const int n = i / 25, k4 = (i % 25) * 4;
            const float4 v = *(const float4*)&W2[n * 100 + k4];
            *(uint2*)&ar[OFF_S + n * S + k4] = make_uint2(pk2(v.x, v.y), pk2(v.z, v.w));
        }
        for (int i = tid; i < 140; i += 448) {            // W2 k-pad zero
            const int n = i / 7, j = (i % 7) * 4;
            *(uint2*)&ar[OFF_S + n * S + 100 + j] = make_uint2(0u, 0u);
        }
        for (int i = tid; i < 700; i += 448) {            // OFF_F k-pad zero (rows 0-99)
            const int n = i / 7, j = (i % 7) * 4;
            *(uint2*)&ar[OFF_F + n * S + 100 + j] = make_uint2(0u, 0u);
        }
        for (int i = tid; i < 140; i += 448) {            // T2t rows 0-19 k-pad zero
            const int n = i / 7, j = (i % 7) * 4;
            *(uint2*)&ar[OFF_T2 + n * S + 100 + j] = make_uint2(0u, 0u);
        }

        // --- GEMM1: C = feat @ W1^T, B streamed from global (L2-hot) ---
        f32x4 acc[7];
        {
            const f32x4 z = {0.f, 0.f, 0.f, 0.f};
            #pragma unroll
            for (int n = 0; n < 7; ++n) acc[n] = z;
        }
        #pragma unroll
        for (int ks = 0; ks < 3; ++ks) {
            const int k = ks * 32 + lq * 8;
            bf16x8 bf[7];
            #pragma unroll
            for (int n = 0; n < 7; ++n) {
                int brow = n * 16 + lm; if (brow > 99) brow = 99;  // clamp: no OOB, C cols discarded
                const float* p = W1 + brow * 100 + k;
                bf[n] = pk8(*(const float4*)p, *(const float4*)(p + 4));
            }
            #pragma unroll
            for (int n = 0; n < 7; ++n)
                acc[n] = __builtin_amdgcn_mfma_f32_16x16x32_bf16(afrag[ks], bf[n], acc[n], 0, 0, 0);
        }
        {   // ks = 3: k 96..127, only lq==0 carries data (k 96..99)
            const float4 z4 = make_float4(0.f, 0.f, 0.f, 0.f);
            bf16x8 bf[7];
            #pragma unroll
            for (int n = 0; n < 7; ++n) {
                int brow = n * 16 + lm; if (brow > 99) brow = 99;
                const float4 a = (lq == 0) ? *(const float4*)&W1[brow * 100 + 96] : z4;
                bf[n] = pk8(a, z4);
            }
            #pragma unroll
            for (int n = 0; n < 7; ++n)
                acc[n] = __builtin_amdgcn_mfma_f32_16x16x32_bf16(afrag[3], bf[n], acc[n], 0, 0, 0);
        }
        // --- T1t epilogue: row=f1, col=node. OFF_F holds nothing GEMM1 reads;
        //     each wave writes only its own cols -> no barrier needed before this.
        {
            const int m0 = w * 16 + lq * 4;               // node
            #pragma unroll
            for (int n = 0; n < 7; ++n) {
                const int cc = n * 16 + lm;               // f1
                if (cc < 100 && m0 <= 96) st4bf(&ar[OFF_F + cc * S + m0], acc[n]);
            }
        }
    } else {
        // ---- wave 7: edges + A-build + V-dots + Z-dots (all global inputs) ----
        const int base = g * 100;
        int e1[16], e2[16];
        {
            const int* ep = edge_src + g * 1600 + lane * 16;
            int4 e;
            e = *(const int4*)&ep[0];  e1[0]=e.x;  e1[1]=e.y;  e1[2]=e.z;  e1[3]=e.w;
            e = *(const int4*)&ep[4];  e1[4]=e.x;  e1[5]=e.y;  e1[6]=e.z;  e1[7]=e.w;
            e = *(const int4*)&ep[8];  e1[8]=e.x;  e1[9]=e.y;  e1[10]=e.z; e1[11]=e.w;
            e = *(const int4*)&ep[12]; e1[12]=e.x; e1[13]=e.y; e1[14]=e.z; e1[15]=e.w;
            #pragma unroll
            for (int i = 0; i < 16; ++i) e1[i] -= base;
        }
        const bool r2 = (lane < 36);
        if (r2) {
            const int* ep = edge_src + g * 1600 + (64 + lane) * 16;
            int4 e;
            e = *(const int4*)&ep[0];  e2[0]=e.x;  e2[1]=e.y;  e2[2]=e.z;  e2[3]=e.w;
            e = *(const int4*)&ep[4];  e2[4]=e.x;  e2[5]=e.y;  e2[6]=e.z;  e2[7]=e.w;
            e = *(const int4*)&ep[8];  e2[8]=e.x;  e2[9]=e.y;  e2[10]=e.z; e2[11]=e.w;
            e = *(const int4*)&ep[12]; e2[12]=e.x; e2[13]=e.y; e2[14]=e.z; e2[15]=e.w;
            #pragma unroll
            for (int i = 0; i < 16; ++i) e2[i] -= base;
        }
        // V2/V3 (global reads; pair-split over feature dim)
        const int j = lane >> 1, h = lane & 1;
        {
            const float* wr = Wv2 + j * 200 + h * 100;
            const float* xr = self_feat + g * 200 + h * 100;
            float s = 0.f;
            for (int c = 0; c < 25; ++c) {
                const float4 a = *(const float4*)&wr[c * 4];
                const float4 x = *(const float4*)&xr[c * 4];
                s += a.x * x.x + a.y * x.y + a.z * x.z + a.w * x.w;
            }
            s += __shfl_xor(s, 1);
            if (h == 0) fl[FV2 + j] = s;
        }
        {
            const float* wr = Wv3 + j * 100;
            const float* xr = x3d + g * 100;
            const int c0 = h ? 13 : 0, c1 = h ? 25 : 13;
            float s = 0.f;
            for (int c = c0; c < c1; ++c) {
                const float4 a = *(const float4*)&wr[c * 4];
                const float4 x = *(const float4*)&xr[c * 4];
                s += a.x * x.x + a.y * x.y + a.z * x.z + a.w * x.w;
            }
            s += __shfl_xor(s, 1);
            if (h == 0) fl[FV3 + j] = s;
        }
        // A-build: zero (stagger by row>>3: conflict groups are row mod 8) + scatter
        {
            const uint4 z4i = make_uint4(0u, 0u, 0u, 0u);
            const int r = lane;
            const int st = (r >> 3) % 17;
            #pragma unroll
            for (int pp = 0; pp < 17; ++pp) {
                int p = pp + st; if (p >= 17) p -= 17;
                *(uint4*)&ar[OFF_A + r * S + p * 8] = z4i;
            }
            #pragma unroll
            for (int i = 0; i < 16; ++i) {
                int cnt = 0;
                #pragma unroll
                for (int jj = 0; jj < 16; ++jj) cnt += (e1[jj] == e1[i]);
                ar[OFF_A + r * S + e1[i]] = bf16rne((float)cnt * 0.0625f);  // idempotent
            }
        }
        if (r2) {
            const uint4 z4i = make_uint4(0u, 0u, 0u, 0u);
            const int r = 64 + lane;
            const int st = (r >> 3) % 17;
            #pragma unroll
            for (int pp = 0; pp < 17; ++pp) {
                int p = pp + st; if (p >= 17) p -= 17;
                *(uint4*)&ar[OFF_A + r * S + p * 8] = z4i;
            }
            #pragma unroll
            for (int i = 0; i < 16; ++i) {
                int cnt = 0;
                #pragma unroll
                for (int jj = 0; jj < 16; ++jj) cnt += (e2[jj] == e2[i]);
                ar[OFF_A + r * S + e2[i]] = bf16rne((float)cnt * 0.0625f);
            }
        }
        // Z2/Z3 from same-wave V values (in-wave LDS RAW: compiler waits lgkmcnt)
        if (lane < 20) {
            const float* wr = Wo2 + lane * 32;
            float s = 0.f;
            #pragma unroll
            for (int c = 0; c < 8; ++c) {
                const float4 a = *(const float4*)&wr[c * 4];
                s += a.x * fl[FV2 + c * 4] + a.y * fl[FV2 + c * 4 + 1]
                   + a.z * fl[FV2 + c * 4 + 2] + a.w * fl[FV2 + c * 4 + 3];
            }
            fl[FZ2 + lane] = s;
        } else if (lane < 40) {
            const int jz = lane - 20;
            const float* wr = Wo3 + jz * 32;
            float s = 0.f;
            #pragma unroll
            for (int c = 0; c < 8; ++c) {
                const float4 a = *(const float4*)&wr[c * 4];
                s += a.x * fl[FV3 + c * 4] + a.y * fl[FV3 + c * 4 + 1]
                   + a.z * fl[FV3 + c * 4 + 2] + a.w * fl[FV3 + c * 4 + 3];
            }
            fl[FZ3 + jz] = s;
        }
    }
    __syncthreads();   // B1

    // ================= P3: GEMM2 C2t[f1][dst] = T1t @ A (waves 0-6) ==============
    f32x4 acc2[7];
    {
        const f32x4 z = {0.f, 0.f, 0.f, 0.f};
        #pragma unroll
        for (int n = 0; n < 7; ++n) acc2[n] = z;
    }
    if (w < 7) gemm_row<7>(ar, OFF_F, OFF_A, w, lm, lq, acc2);
    __syncthreads();   // B2

    // ================= P4: h1 = relu(C2 + b1), node-major writes =================
    if (w < 7) {
        const int m0 = w * 16 + lq * 4;                   // f1 base
        if (m0 <= 96) {
            const float4 bb = *(const float4*)&fl[FB1 + m0];
            #pragma unroll
            for (int n = 0; n < 7; ++n) {
                const int cc = n * 16 + lm;               // dst node
                if (cc < 100) {
                    f32x4 v = acc2[n];
                    v[0] = fmaxf(v[0] + bb.x, 0.f); v[1] = fmaxf(v[1] + bb.y, 0.f);
                    v[2] = fmaxf(v[2] + bb.z, 0.f); v[3] = fmaxf(v[3] + bb.w, 0.f);
                    st4bf(&ar[OFF_F + cc * S + m0], v);
                }
            }
        }
    }
    __syncthreads();   // B3

    // ================= P5: GEMM3 T2t[f2][node] = W2p @ h1 (all 8 waves) ==========
    const int mt  = w & 1;
    const int ntA = w >> 1;            // 0..3
    const bool hasB = (w < 6);
    const int ntB = 4 + (w >> 1);      // 4..6
    {
        const f32x4 z = {0.f, 0.f, 0.f, 0.f};
        f32x4 cA = z, cB = z;
        #pragma unroll
        for (int ks = 0; ks < 4; ++ks) {
            const int k = ks * 32 + lq * 8;
            bf16x8 a = *(const bf16x8*)&ar[OFF_S + (mt * 16 + lm) * S + k];
            bf16x8 bA = *(const bf16x8*)&ar[OFF_F + (ntA * 16 + lm) * S + k];
            cA = __builtin_amdgcn_mfma_f32_16x16x32_bf16(a, bA, cA, 0, 0, 0);
            if (hasB) {
                bf16x8 bB = *(const bf16x8*)&ar[OFF_F + (ntB * 16 + lm) * S + k];
                cB = __builtin_amdgcn_mfma_f32_16x16x32_bf16(a, bB, cB, 0, 0, 0);
            }
        }
        const int ccA = ntA * 16 + lm;
        if (ccA < 100) {
            #pragma unroll
            for (int r = 0; r < 4; ++r) {
                const int f2 = mt * 16 + lq * 4 + r;
                if (f2 < 20) ar[OFF_T2 + f2 * S + ccA] = bf16rne(cA[r]);
            }
        }
        if (hasB) {
            const int ccB = ntB * 16 + lm;
            if (ccB < 100) {
                #pragma unroll
                for (int r = 0; r < 4; ++r) {
                    const int f2 = mt * 16 + lq * 4 + r;
                    if (f2 < 20) ar[OFF_T2 + f2 * S + ccB] = bf16rne(cB[r]);
                }
            }
        }
    }
    __syncthreads();   // B4

    // ================= P6: GEMM4 C4t[f2][dst] = T2t @ A; relu+b2 partials ========
    {
        const f32x4 z = {0.f, 0.f, 0.f, 0.f};
        f32x4 cA = z, cB = z;
        #pragma unroll
        for (int ks = 0; ks < 4; ++ks) {
            const int k = ks * 32 + lq * 8;
            bf16x8 a = *(const bf16x8*)&ar[OFF_T2 + (mt * 16 + lm) * S + k];
            bf16x8 bA = *(const bf16x8*)&ar[OFF_A + (ntA * 16 + lm) * S + k];
            cA = __builtin_amdgcn_mfma_f32_16x16x32_bf16(a, bA, cA, 0, 0, 0);
            if (hasB) {
                bf16x8 bB = *(const bf16x8*)&ar[OFF_A + (ntB * 16 + lm) * S + k];
                cB = __builtin_amdgcn_mfma_f32_16x16x32_bf16(a, bB, cB, 0, 0, 0);
            }
        }
        const int ccA = ntA * 16 + lm;
        const int ccB = ntB * 16 + lm;
        #pragma unroll
        for (int r = 0; r < 4; ++r) {
            const int f2 = mt * 16 + lq * 4 + r;
            const bool fv = (f2 < 20);
            const float bias = fv ? fl[FB2 + (fv ? f2 : 0)] : 0.f;
            float val = (fv && ccA < 100) ? fmaxf(cA[r] + bias, 0.f) : 0.f;
            if (hasB && fv && ccB < 100) val += fmaxf(cB[r] + bias, 0.f);
            val += __shfl_xor(val, 1);
            val += __shfl_xor(val, 2);
            val += __shfl_xor(val, 4);
            val += __shfl_xor(val, 8);
            if (lm == 0 && fv) fl[FHGP + (w >> 1) * 20 + f2] = val;  // collision-free
        }
    }
    __syncthreads();   // B5

    // ================= P7: tail on wave 0 (all params in LDS) ====================
    if (tid < 64) {
        const int j = tid;
        float y = 0.f;
        if (j < 20) {
            y = fl[FHGP + j] + fl[FHGP + 20 + j] + fl[FHGP + 40 + j] + fl[FHGP + 60 + j];
            y = y * 0.01f + fl[FZ2 + j];
        }
        float s = y;
        s += __shfl_xor(s, 1); s += __shfl_xor(s, 2); s += __shfl_xor(s, 4);
        s += __shfl_xor(s, 8); s += __shfl_xor(s, 16);
        const float mu = s * 0.05f;
        float d = (j < 20) ? (y - mu) : 0.f;
        float v = d * d;
        v += __shfl_xor(v, 1); v += __shfl_xor(v, 2); v += __shfl_xor(v, 4);
        v += __shfl_xor(v, 8); v += __shfl_xor(v, 16);
        const float inv1 = 1.f / sqrtf(v * 0.05f + LN_EPS);
        float y2 = 0.f;
        if (j < 20) y2 = d * inv1 * fl[FG2 + j] + fl[FBE2 + j] + fl[FZ3 + j];
        float s2 = y2;
        s2 += __shfl_xor(s2, 1); s2 += __shfl_xor(s2, 2); s2 += __shfl_xor(s2, 4);
        s2 += __shfl_xor(s2, 8); s2 += __shfl_xor(s2, 16);
        const float mu2 = s2 * 0.05f;
        float d2 = (j < 20) ? (y2 - mu2) : 0.f;
        float v2 = d2 * d2;
        v2 += __shfl_xor(v2, 1); v2 += __shfl_xor(v2, 2); v2 += __shfl_xor(v2, 4);
        v2 += __shfl_xor(v2, 8); v2 += __shfl_xor(v2, 16);
        const float inv2 = 1.f / sqrtf(v2 * 0.05f + LN_EPS);
        float y3 = 0.f;
        if (j < 20) y3 = d2 * inv2 * fl[FG3 + j] + fl[FBE3 + j];

        // MLP: broadcast shuffles with ALL 64 lanes active (CDNA reads from
        // inactive src lanes return 0 -- R3 lesson).
        float acc7 = 0.f;
        {
            const int js = (j < 10) ? j : 0;
            #pragma unroll
            for (int k = 0; k < 20; ++k) {
                const float yk = __shfl(y3, k);
                acc7 += fl[FWF1 + js * 20 + k] * yk;
            }
            const float bias = fl[FBF1 + js];
            const float w2v  = fl[FWF2 + js];
            acc7 = (j < 10) ? fmaxf(acc7 + bias, 0.f) * w2v : 0.f;
        }
        acc7 += __shfl_xor(acc7, 1); acc7 += __shfl_xor(acc7, 2);
        acc7 += __shfl_xor(acc7, 4); acc7 += __shfl_xor(acc7, 8);
        if (j == 0) out[g] = acc7 + fl[FBF2];
    }
}

extern "C" void kernel_launch(void* const* d_in, const int* in_sizes, int n_in,
                              void* d_out, int out_size, void* d_ws, size_t ws_size,
                              hipStream_t stream) {
    const float* feat      = (const float*)d_in[0];
    const int*   edge_src  = (const int*)  d_in[1];
    // d_in[2] = edge_dst (implicit: node n's edges at n*16..n*16+15)
    const float* self_feat = (const float*)d_in[3];
    const float* x3d       = (const float*)d_in[4];
    const float* W1  = (const float*)d_in[5];
    const float* b1  = (const float*)d_in[6];
    const float* W2  = (const float*)d_in[7];
    const float* b2  = (const float*)d_in[8];
    // d_in[9]=Wq2, d_in[10]=Wk2 unused (length-1 softmax == 1)
    const float* Wv2 = (const float*)d_in[11];
    const float* Wo2 = (const float*)d_in[12];
    const float* g2  = (const float*)d_in[13];
    const float* be2 = (const float*)d_in[14];
    // d_in[15]=Wq3, d_in[16]=Wk3 unused
    const float* Wv3 = (const float*)d_in[17];
    const float* Wo3 = (const float*)d_in[18];
    const float* g3  = (const float*)d_in[19];
    const float* be3 = (const float*)d_in[20];
    const float* Wf1 = (const float*)d_in[21];
    const float* bf1 = (const float*)d_in[22];
    const float* Wf2 = (const float*)d_in[23];
    const float* bf2 = (const float*)d_in[24];

    fused_net_v7<<<512, 512, 0, stream>>>(feat, edge_src, self_feat, x3d,
                                          W1, b1, W2, b2,
                                          Wv2, Wo2, g2, be2,
                                          Wv3, Wo3, g3, be3,
                                          Wf1, bf1, Wf2, bf2,
                                          (float*)d_out);
}

// Round 8
// 133.732 us; speedup vs baseline: 1.0239x; 1.0239x over previous
//
#include <hip/hip_runtime.h>
#include <hip/hip_bf16.h>

#define LN_EPS 1e-5f

typedef __attribute__((ext_vector_type(8))) short bf16x8;
typedef __attribute__((ext_vector_type(4))) float f32x4;

// ---- LDS arena (ushort units). Row stride S=136 (272 B, 16B-aligned;
// bank offset 68 dw == 4 mod 32 -> only free 2-way conflicts).
// NO dedicated spill rows: all n/m-tile overreads land in the NEXT region,
// which is always finite, and contaminate only masked C rows/cols. ----
#define S 136
#define OFF_F  0      // T1t -> h1 (rows 0-99); row-spill reads -> OFF_A (finite)
#define OFF_A  13600  // W1p -> agg A (rows 0-99); spill reads -> OFF_S (finite)
#define OFF_S  27200  // W2p (rows 0-19); spill reads -> OFF_T2 (masked C rows)
#define OFF_T2 29920  // T2t (rows 0-19); spill reads -> FLT floats (masked C rows)
#define FLT    32640  // float scratch (832 floats incl. spill-read margin)
#define ARENA_U 34304 // 68608 B; x2 blocks = 137.2 KB <= 160 KB

// float-region indices
#define FB1  0    // b1 [100]
#define FB2  100  // b2 [20]
#define FG2  120
#define FBE2 140
#define FG3  160
#define FBE3 180
#define FWF1 200  // Wf1 [200]
#define FBF1 400  // bf1 [10] (+pad)
#define FWF2 412  // Wf2 [10] (+pad)
#define FBF2 424  // bf2 [1] (+pad)
#define FV2  428  // V2 [32]
#define FV3  460  // V3 [32]
#define FZ2  492  // Z2 [20]
#define FZ3  512  // Z3 [20]
#define FHGP 532  // hg partials [7][20] (fully overwritten in P6 -> no init)

__device__ __forceinline__ unsigned short bf16rne(float x) {
    union { float f; unsigned u; } v; v.f = x;
    unsigned r = (v.u + 0x7FFFu + ((v.u >> 16) & 1u)) >> 16;
    return (unsigned short)r;
}

__device__ __forceinline__ unsigned pk2(float a, float b) {
    __hip_bfloat162 h = __float22bfloat162_rn(float2{a, b});
    unsigned r; __builtin_memcpy(&r, &h, 4); return r;
}

__device__ __forceinline__ void st4bf(unsigned short* p, const f32x4 v) {
    *(uint2*)p = make_uint2(pk2(v[0], v[1]), pk2(v[2], v[3]));
}

__device__ __forceinline__ bf16x8 pk8(const float4 a, const float4 b) {
    union { bf16x8 v; uint4 u; } r;
    r.u = make_uint4(pk2(a.x, a.y), pk2(a.z, a.w), pk2(b.x, b.y), pk2(b.z, b.w));
    return r.v;
}

// One block per graph, 1024 threads (16 waves): 8 waves/SIMD at 2 blocks/CU
// (2048 threads/CU = HW max). VGPR capped at 64 by launch bounds.
__global__ __launch_bounds__(1024, 8) void fused_net_v8(
    const float* __restrict__ feat, const int* __restrict__ edge_src,
    const float* __restrict__ self_feat, const float* __restrict__ x3d,
    const float* __restrict__ W1, const float* __restrict__ b1,
    const float* __restrict__ W2, const float* __restrict__ b2,
    const float* __restrict__ Wv2, const float* __restrict__ Wo2,
    const float* __restrict__ g2, const float* __restrict__ be2,
    const float* __restrict__ Wv3, const float* __restrict__ Wo3,
    const float* __restrict__ g3, const float* __restrict__ be3,
    const float* __restrict__ Wf1, const float* __restrict__ bf1,
    const float* __restrict__ Wf2, const float* __restrict__ bf2,
    float* __restrict__ out)
{
    __shared__ __align__(16) unsigned short ar[ARENA_U];
    float* fl = (float*)&ar[FLT];

    const int g    = blockIdx.x;
    const int tid  = threadIdx.x;
    const int w    = tid >> 6;      // 0..15
    const int lane = tid & 63;
    const int lm   = lane & 15;
    const int lq   = lane >> 4;

    // GEMM1/2 split: waves 0-13 -> (m-tile mw = w>>1 in 0..6) x (n-half nh = w&1)
    const int mw  = w >> 1;
    const int nh  = w & 1;
    const int nlo = nh ? 4 : 0;
    const int nnt = nh ? 3 : 4;      // n-tiles: nh0 -> {0..3}, nh1 -> {4..6}
    // GEMM3/4 split: waves 0-13 -> (mt = w&1) x (nt3 = w>>1 in 0..6)
    const int mt  = w & 1;
    const int nt3 = w >> 1;

    bf16x8 afrag[4];   // feat A-fragments (waves 0-13)
    int e1[16], e2[16];  // edge rows (wave 14)

    // ================= P0: stage everything =================
    // params -> LDS float region (low tids; their staging work below is light)
    if (tid < 25)       *(float4*)&fl[FB1 + tid * 4]          = *(const float4*)&b1[tid * 4];
    else if (tid < 30)  *(float4*)&fl[FB2 + (tid - 25) * 4]   = *(const float4*)&b2[(tid - 25) * 4];
    else if (tid < 35)  *(float4*)&fl[FG2 + (tid - 30) * 4]   = *(const float4*)&g2[(tid - 30) * 4];
    else if (tid < 40)  *(float4*)&fl[FBE2 + (tid - 35) * 4]  = *(const float4*)&be2[(tid - 35) * 4];
    else if (tid < 45)  *(float4*)&fl[FG3 + (tid - 40) * 4]   = *(const float4*)&g3[(tid - 40) * 4];
    else if (tid < 50)  *(float4*)&fl[FBE3 + (tid - 45) * 4]  = *(const float4*)&be3[(tid - 45) * 4];
    else if (tid < 100) *(float4*)&fl[FWF1 + (tid - 50) * 4]  = *(const float4*)&Wf1[(tid - 50) * 4];
    else if (tid < 110) { const int j = tid - 100; fl[FBF1 + j] = bf1[j]; fl[FWF2 + j] = Wf2[j]; }
    else if (tid == 110) fl[FBF2] = bf2[0];

    if (w < 14) {
        // feat -> A-fragments (its only consumer); loads overlap W1 staging
        int am = mw * 16 + lm; if (am > 99) am = 99;   // clamp -> masked C rows
        const float* frow = feat + g * 10000 + am * 100;
        #pragma unroll
        for (int ks = 0; ks < 3; ++ks) {
            const int k = ks * 32 + lq * 8;
            afrag[ks] = pk8(*(const float4*)&frow[k], *(const float4*)&frow[k + 4]);
        }
        const float4 z4 = make_float4(0.f, 0.f, 0.f, 0.f);
        afrag[3] = (lq == 0) ? pk8(*(const float4*)&frow[96], z4) : pk8(z4, z4);
    } else if (w == 14) {
        // edge preload: rows 0-63 (all lanes), rows 64-99 (lanes 0-35)
        const int base = g * 100;
        const int* ep = edge_src + g * 1600 + lane * 16;
        int4 e;
        e = *(const int4*)&ep[0];  e1[0]=e.x;  e1[1]=e.y;  e1[2]=e.z;  e1[3]=e.w;
        e = *(const int4*)&ep[4];  e1[4]=e.x;  e1[5]=e.y;  e1[6]=e.z;  e1[7]=e.w;
        e = *(const int4*)&ep[8];  e1[8]=e.x;  e1[9]=e.y;  e1[10]=e.z; e1[11]=e.w;
        e = *(const int4*)&ep[12]; e1[12]=e.x; e1[13]=e.y; e1[14]=e.z; e1[15]=e.w;
        #pragma unroll
        for (int i = 0; i < 16; ++i) e1[i] -= base;
        if (lane < 36) {
            const int* ep2 = edge_src + g * 1600 + (64 + lane) * 16;
            e = *(const int4*)&ep2[0];  e2[0]=e.x;  e2[1]=e.y;  e2[2]=e.z;  e2[3]=e.w;
            e = *(const int4*)&ep2[4];  e2[4]=e.x;  e2[5]=e.y;  e2[6]=e.z;  e2[7]=e.w;
            e = *(const int4*)&ep2[8];  e2[8]=e.x;  e2[9]=e.y;  e2[10]=e.z; e2[11]=e.w;
            e = *(const int4*)&ep2[12]; e2[12]=e.x; e2[13]=e.y; e2[14]=e.z; e2[15]=e.w;
            #pragma unroll
            for (int i = 0; i < 16; ++i) e2[i] -= base;
        }
    }

    // cooperative staging (all 1024 threads)
    for (int i = tid; i < 2500; i += 1024) {           // W1 -> OFF_A bf16
        const int n = i / 25, k4 = (i % 25) * 4;
        const float4 v = *(const float4*)&W1[n * 100 + k4];
        *(uint2*)&ar[OFF_A + n * S + k4] = make_uint2(pk2(v.x, v.y), pk2(v.z, v.w));
    }
    for (int i = tid; i < 700; i += 1024) {            // W1 k-pad zero
        const int n = i / 7, j = (i % 7) * 4;
        *(uint2*)&ar[OFF_A + n * S + 100 + j] = make_uint2(0u, 0u);
    }
    for (int i = tid; i < 700; i += 1024) {            // OFF_F k-pad zero
        const int n = i / 7, j = (i % 7) * 4;
        *(uint2*)&ar[OFF_F + n * S + 100 + j] = make_uint2(0u, 0u);
    }
    for (int i = tid; i < 500; i += 1024) {            // W2 -> OFF_S bf16
        const int n = i / 25, k4 = (i % 25) * 4;
        const float4 v = *(const float4*)&W2[n * 100 + k4];
        *(uint2*)&ar[OFF_S + n * S + k4] = make_uint2(pk2(v.x, v.y), pk2(v.z, v.w));
    }
    for (int i = tid; i < 140; i += 1024) {            // W2 k-pad zero
        const int n = i / 7, j = (i % 7) * 4;
        *(uint2*)&ar[OFF_S + n * S + 100 + j] = make_uint2(0u, 0u);
    }
    for (int i = tid; i < 140; i += 1024) {            // T2t rows 0-19 k-pad zero
        const int n = i / 7, j = (i % 7) * 4;
        *(uint2*)&ar[OFF_T2 + n * S + 100 + j] = make_uint2(0u, 0u);
    }
    __syncthreads();   // B0

    // ================= P1: GEMM1 (waves 0-13) + T1t epi; V-dots (wave 15) =======
    if (w < 14) {
        f32x4 acc[4];
        {
            const f32x4 z = {0.f, 0.f, 0.f, 0.f};
            #pragma unroll
            for (int n = 0; n < 4; ++n) acc[n] = z;
        }
        #pragma unroll
        for (int ks = 0; ks < 4; ++ks) {
            const int k = ks * 32 + lq * 8;
            #pragma unroll
            for (int n = 0; n < 4; ++n) {
                if (n < nnt) {
                    bf16x8 b = *(const bf16x8*)&ar[OFF_A + ((nlo + n) * 16 + lm) * S + k];
                    acc[n] = __builtin_amdgcn_mfma_f32_16x16x32_bf16(afrag[ks], b, acc[n], 0, 0, 0);
                }
            }
        }
        // T1t epilogue: row = f1 (n-tile), col = node (m-tile). Disjoint per wave.
        const int m0 = mw * 16 + lq * 4;
        #pragma unroll
        for (int n = 0; n < 4; ++n) {
            if (n < nnt) {
                const int cc = (nlo + n) * 16 + lm;            // f1
                if (cc < 100 && m0 <= 96) st4bf(&ar[OFF_F + cc * S + m0], acc[n]);
            }
        }
    } else if (w == 15) {
        // V2/V3 dots from global (pair-split over feature dim)
        const int j = lane >> 1, h = lane & 1;
        {
            const float* wr = Wv2 + j * 200 + h * 100;
            const float* xr = self_feat + g * 200 + h * 100;
            float s = 0.f;
            for (int c = 0; c < 25; ++c) {
                const float4 a = *(const float4*)&wr[c * 4];
                const float4 x = *(const float4*)&xr[c * 4];
                s += a.x * x.x + a.y * x.y + a.z * x.z + a.w * x.w;
            }
            s += __shfl_xor(s, 1);
            if (h == 0) fl[FV2 + j] = s;
        }
        {
            const float* wr = Wv3 + j * 100;
            const float* xr = x3d + g * 100;
            const int c0 = h ? 13 : 0, c1 = h ? 25 : 13;
            float s = 0.f;
            for (int c = c0; c < c1; ++c) {
                const float4 a = *(const float4*)&wr[c * 4];
                const float4 x = *(const float4*)&xr[c * 4];
                s += a.x * x.x + a.y * x.y + a.z * x.z + a.w * x.w;
            }
            s += __shfl_xor(s, 1);
            if (h == 0) fl[FV3 + j] = s;
        }
    }
    __syncthreads();   // B1

    // ================= P2: A-build (wave 14) + Z-dots (wave 15) ==================
    if (w == 14) {
        const uint4 z4i = make_uint4(0u, 0u, 0u, 0u);
        {   // rows 0-63
            const int r = lane;
            const int st = (r >> 3) % 17;             // conflict groups are row mod 8
            #pragma unroll
            for (int pp = 0; pp < 17; ++pp) {
                int p = pp + st; if (p >= 17) p -= 17;
                *(uint4*)&ar[OFF_A + r * S + p * 8] = z4i;
            }
            #pragma unroll
            for (int i = 0; i < 16; ++i) {
                int cnt = 0;
                #pragma unroll
                for (int jj = 0; jj < 16; ++jj) cnt += (e1[jj] == e1[i]);
                ar[OFF_A + r * S + e1[i]] = bf16rne((float)cnt * 0.0625f);  // idempotent
            }
        }
        if (lane < 36) {   // rows 64-99
            const int r = 64 + lane;
            const int st = (r >> 3) % 17;
            #pragma unroll
            for (int pp = 0; pp < 17; ++pp) {
                int p = pp + st; if (p >= 17) p -= 17;
                *(uint4*)&ar[OFF_A + r * S + p * 8] = z4i;
            }
            #pragma unroll
            for (int i = 0; i < 16; ++i) {
                int cnt = 0;
                #pragma unroll
                for (int jj = 0; jj < 16; ++jj) cnt += (e2[jj] == e2[i]);
                ar[OFF_A + r * S + e2[i]] = bf16rne((float)cnt * 0.0625f);
            }
        }
    } else if (w == 15) {
        if (lane < 20) {
            const float* wr = Wo2 + lane * 32;
            float s = 0.f;
            #pragma unroll
            for (int c = 0; c < 8; ++c) {
                const float4 a = *(const float4*)&wr[c * 4];
                s += a.x * fl[FV2 + c * 4] + a.y * fl[FV2 + c * 4 + 1]
                   + a.z * fl[FV2 + c * 4 + 2] + a.w * fl[FV2 + c * 4 + 3];
            }
            fl[FZ2 + lane] = s;
        } else if (lane < 40) {
            const int jz = lane - 20;
            const float* wr = Wo3 + jz * 32;
            float s = 0.f;
            #pragma unroll
            for (int c = 0; c < 8; ++c) {
                const float4 a = *(const float4*)&wr[c * 4];
                s += a.x * fl[FV3 + c * 4] + a.y * fl[FV3 + c * 4 + 1]
                   + a.z * fl[FV3 + c * 4 + 2] + a.w * fl[FV3 + c * 4 + 3];
            }
            fl[FZ3 + jz] = s;
        }
    }
    __syncthreads();   // B2

    // ================= P3: GEMM2 C2t[f1][dst] = T1t @ A (waves 0-13) =============
    f32x4 acc2[4];
    {
        const f32x4 z = {0.f, 0.f, 0.f, 0.f};
        #pragma unroll
        for (int n = 0; n < 4; ++n) acc2[n] = z;
    }
    if (w < 14) {
        #pragma unroll
        for (int ks = 0; ks < 4; ++ks) {
            const int k = ks * 32 + lq * 8;
            bf16x8 a = *(const bf16x8*)&ar[OFF_F + (mw * 16 + lm) * S + k];
            #pragma unroll
            for (int n = 0; n < 4; ++n) {
                if (n < nnt) {
                    bf16x8 b = *(const bf16x8*)&ar[OFF_A + ((nlo + n) * 16 + lm) * S + k];
                    acc2[n] = __builtin_amdgcn_mfma_f32_16x16x32_bf16(a, b, acc2[n], 0, 0, 0);
                }
            }
        }
    }
    __syncthreads();   // B3

    // ================= P4: h1 = relu(C2 + b1), node-major writes =================
    if (w < 14) {
        const int m0 = mw * 16 + lq * 4;               // f1 base
        if (m0 <= 96) {
            const float4 bb = *(const float4*)&fl[FB1 + m0];
            #pragma unroll
            for (int n = 0; n < 4; ++n) {
                if (n < nnt) {
                    const int cc = (nlo + n) * 16 + lm;   // dst node
                    if (cc < 100) {
                        f32x4 v = acc2[n];
                        v[0] = fmaxf(v[0] + bb.x, 0.f); v[1] = fmaxf(v[1] + bb.y, 0.f);
                        v[2] = fmaxf(v[2] + bb.z, 0.f); v[3] = fmaxf(v[3] + bb.w, 0.f);
                        st4bf(&ar[OFF_F + cc * S + m0], v);
                    }
                }
            }
        }
    }
    __syncthreads();   // B4

    // ================= P5: GEMM3 T2t[f2][node] = W2p @ h1 (waves 0-13) ===========
    if (w < 14) {
        const f32x4 z = {0.f, 0.f, 0.f, 0.f};
        f32x4 c = z;
        #pragma unroll
        for (int ks = 0; ks < 4; ++ks) {
            const int k = ks * 32 + lq * 8;
            bf16x8 a = *(const bf16x8*)&ar[OFF_S + (mt * 16 + lm) * S + k];
            bf16x8 b = *(const bf16x8*)&ar[OFF_F + (nt3 * 16 + lm) * S + k];
            c = __builtin_amdgcn_mfma_f32_16x16x32_bf16(a, b, c, 0, 0, 0);
        }
        const int cc = nt3 * 16 + lm;                  // node
        if (cc < 100) {
            #pragma unroll
            for (int r = 0; r < 4; ++r) {
                const int f2 = mt * 16 + lq * 4 + r;
                if (f2 < 20) ar[OFF_T2 + f2 * S + cc] = bf16rne(c[r]);
            }
        }
    }
    __syncthreads();   // B5

    // ================= P6: GEMM4 C4t[f2][dst] = T2t @ A; relu+b2 partials ========
    if (w < 14) {
        const f32x4 z = {0.f, 0.f, 0.f, 0.f};
        f32x4 c = z;
        #pragma unroll
        for (int ks = 0; ks < 4; ++ks) {
            const int k = ks * 32 + lq * 8;
            bf16x8 a = *(const bf16x8*)&ar[OFF_T2 + (mt * 16 + lm) * S + k];
            bf16x8 b = *(const bf16x8*)&ar[OFF_A + (nt3 * 16 + lm) * S + k];
            c = __builtin_amdgcn_mfma_f32_16x16x32_bf16(a, b, c, 0, 0, 0);
        }
        const int cc = nt3 * 16 + lm;                  // dst
        #pragma unroll
        for (int r = 0; r < 4; ++r) {
            const int f2 = mt * 16 + lq * 4 + r;
            const bool fv = (f2 < 20);
            const float bias = fv ? fl[FB2 + (fv ? f2 : 0)] : 0.f;
            float val = (fv && cc < 100) ? fmaxf(c[r] + bias, 0.f) : 0.f;
            val += __shfl_xor(val, 1);
            val += __shfl_xor(val, 2);
            val += __shfl_xor(val, 4);
            val += __shfl_xor(val, 8);
            // slot nt3 (0..6); mt=0 writes f2 0-15, mt=1 writes 16-19: collision-free
            if (lm == 0 && fv) fl[FHGP + nt3 * 20 + f2] = val;
        }
    }
    __syncthreads();   // B6

    // ================= P7: tail on wave 0 (all params in LDS) ====================
    if (tid < 64) {
        const int j = tid;
        float y = 0.f;
        if (j < 20) {
            y = fl[FHGP + j];
            #pragma unroll
            for (int sft = 1; sft < 7; ++sft) y += fl[FHGP + sft * 20 + j];
            y = y * 0.01f + fl[FZ2 + j];
        }
        float s = y;
        s += __shfl_xor(s, 1); s += __shfl_xor(s, 2); s += __shfl_xor(s, 4);
        s += __shfl_xor(s, 8); s += __shfl_xor(s, 16);
        const float mu = s * 0.05f;
        float d = (j < 20) ? (y - mu) : 0.f;
        float v = d * d;
        v += __shfl_xor(v, 1); v += __shfl_xor(v, 2); v += __shfl_xor(v, 4);
        v += __shfl_xor(v, 8); v += __shfl_xor(v, 16);
        const float inv1 = 1.f / sqrtf(v * 0.05f + LN_EPS);
        float y2 = 0.f;
        if (j < 20) y2 = d * inv1 * fl[FG2 + j] + fl[FBE2 + j] + fl[FZ3 + j];
        float s2 = y2;
        s2 += __shfl_xor(s2, 1); s2 += __shfl_xor(s2, 2); s2 += __shfl_xor(s2, 4);
        s2 += __shfl_xor(s2, 8); s2 += __shfl_xor(s2, 16);
        const float mu2 = s2 * 0.05f;
        float d2 = (j < 20) ? (y2 - mu2) : 0.f;
        float v2 = d2 * d2;
        v2 += __shfl_xor(v2, 1); v2 += __shfl_xor(v2, 2); v2 += __shfl_xor(v2, 4);
        v2 += __shfl_xor(v2, 8); v2 += __shfl_xor(v2, 16);
        const float inv2 = 1.f / sqrtf(v2 * 0.05f + LN_EPS);
        float y3 = 0.f;
        if (j < 20) y3 = d2 * inv2 * fl[FG3 + j] + fl[FBE3 + j];

        // MLP: broadcast shuffles with ALL 64 lanes active (CDNA reads from
        // inactive src lanes return 0 -- R3 lesson).
        float acc7 = 0.f;
        {
            const int js = (j < 10) ? j : 0;
            #pragma unroll
            for (int k = 0; k < 20; ++k) {
                const float yk = __shfl(y3, k);
                acc7 += fl[FWF1 + js * 20 + k] * yk;
            }
            const float bias = fl[FBF1 + js];
            const float w2v  = fl[FWF2 + js];
            acc7 = (j < 10) ? fmaxf(acc7 + bias, 0.f) * w2v : 0.f;
        }
        acc7 += __shfl_xor(acc7, 1); acc7 += __shfl_xor(acc7, 2);
        acc7 += __shfl_xor(acc7, 4); acc7 += __shfl_xor(acc7, 8);
        if (j == 0) out[g] = acc7 + fl[FBF2];
    }
}

extern "C" void kernel_launch(void* const* d_in, const int* in_sizes, int n_in,
                              void* d_out, int out_size, void* d_ws, size_t ws_size,
                              hipStream_t stream) {
    const float* feat      = (const float*)d_in[0];
    const int*   edge_src  = (const int*)  d_in[1];
    // d_in[2] = edge_dst (implicit: node n's edges at n*16..n*16+15)
    const float* self_feat = (const float*)d_in[3];
    const float* x3d       = (const float*)d_in[4];
    const float* W1  = (const float*)d_in[5];
    const float* b1  = (const float*)d_in[6];
    const float* W2  = (const float*)d_in[7];
    const float* b2  = (const float*)d_in[8];
    // d_in[9]=Wq2, d_in[10]=Wk2 unused (length-1 softmax == 1)
    const float* Wv2 = (const float*)d_in[11];
    const float* Wo2 = (const float*)d_in[12];
    const float* g2  = (const float*)d_in[13];
    const float* be2 = (const float*)d_in[14];
    // d_in[15]=Wq3, d_in[16]=Wk3 unused
    const float* Wv3 = (const float*)d_in[17];
    const float* Wo3 = (const float*)d_in[18];
    const float* g3  = (const float*)d_in[19];
    const float* be3 = (const float*)d_in[20];
    const float* Wf1 = (const float*)d_in[21];
    const float* bf1 = (const float*)d_in[22];
    const float* Wf2 = (const float*)d_in[23];
    const float* bf2 = (const float*)d_in[24];

    fused_net_v8<<<512, 1024, 0, stream>>>(feat, edge_src, self_feat, x3d,
                                           W1, b1, W2, b2,
                                           Wv2, Wo2, g2, be2,
                                           Wv3, Wo3, g3, be3,
                                           Wf1, bf1, Wf2, bf2,
                                           (float*)d_out);
}

// Round 9
// 130.145 us; speedup vs baseline: 1.0522x; 1.0276x over previous
//
#include <hip/hip_runtime.h>
#include <hip/hip_bf16.h>

#define LN_EPS 1e-5f

typedef __attribute__((ext_vector_type(8))) short bf16x8;
typedef __attribute__((ext_vector_type(4))) float f32x4;

// ---- LDS arena (ushort units). Row stride S=136 (272 B, 16B-aligned;
// bank offset 68 dw == 4 mod 32 -> only free 2-way conflicts). ----
#define S 136
#define OFF_F  0      // feat -> T1t -> h1 (100 rows; spill reads land in A: finite)
#define OFF_A  13600  // W1p (100 rows + 12 spill rows) -> agg A
#define OFF_S  28832  // W2p (32 rows; 20-31 spill -> discarded C rows)
#define OFF_T2 33184  // T2t (rows 0-19 used; 20-31 uninit -> discarded C rows)
#define FLT    37536  // float scratch region
#define ARENA_U 39360 // 78720 B; x2 blocks = 157.4 KB <= 160 KB

// float-region indices
#define FB1  300  // b1 [100]
#define FB2  400  // b2 [20]
#define FG2  420
#define FBE2 440
#define FG3  460
#define FBE3 480
#define FWF1 500  // Wf1 [200]
#define FBF1 700  // bf1 [10] (+pad)
#define FWF2 712  // Wf2 [10] (+pad)
#define FBF2 724  // bf2 [1]  (+pad)
#define FV2  728  // V2 [32]
#define FV3  760  // V3 [32]
#define FZ2  792  // Z2 [20]
#define FZ3  812  // Z3 [20]
#define FHGP 832  // hg partials [4][20] (fully overwritten in P6 -> no init)

__device__ __forceinline__ unsigned short bf16rne(float x) {
    union { float f; unsigned u; } v; v.f = x;
    unsigned r = (v.u + 0x7FFFu + ((v.u >> 16) & 1u)) >> 16;
    return (unsigned short)r;
}

__device__ __forceinline__ unsigned pk2(float a, float b) {
    __hip_bfloat162 h = __float22bfloat162_rn(float2{a, b});
    unsigned r; __builtin_memcpy(&r, &h, 4); return r;
}

__device__ __forceinline__ void st4bf(unsigned short* p, const f32x4 v) {
    *(uint2*)p = make_uint2(pk2(v[0], v[1]), pk2(v[2], v[3]));
}

// K=128 LDS pass, one m-tile row, NT n-tiles. A row-major [m][k]; B as Bt[n][k].
template<int NT>
__device__ __forceinline__ void gemm_row(const unsigned short* __restrict__ ar,
    int Abase, int Bbase, int mrow, int lm, int lq, f32x4 (&acc)[NT])
{
    #pragma unroll
    for (int ks = 0; ks < 4; ++ks) {
        const int k = ks * 32 + lq * 8;
        bf16x8 a = *(const bf16x8*)&ar[Abase + (mrow * 16 + lm) * S + k];
        #pragma unroll
        for (int n = 0; n < NT; ++n) {
            bf16x8 b = *(const bf16x8*)&ar[Bbase + (n * 16 + lm) * S + k];
            acc[n] = __builtin_amdgcn_mfma_f32_16x16x32_bf16(a, b, acc[n], 0, 0, 0);
        }
    }
}

// One block per graph, 512 threads (8 waves): 4 waves/SIMD at 2 blocks/CU.
__global__ __launch_bounds__(512, 4) void fused_net_v9(
    const float* __restrict__ feat, const int* __restrict__ edge_src,
    const float* __restrict__ self_feat, const float* __restrict__ x3d,
    const float* __restrict__ W1, const float* __restrict__ b1,
    const float* __restrict__ W2, const float* __restrict__ b2,
    const float* __restrict__ Wv2, const float* __restrict__ Wo2,
    const float* __restrict__ g2, const float* __restrict__ be2,
    const float* __restrict__ Wv3, const float* __restrict__ Wo3,
    const float* __restrict__ g3, const float* __restrict__ be3,
    const float* __restrict__ Wf1, const float* __restrict__ bf1,
    const float* __restrict__ Wf2, const float* __restrict__ bf2,
    float* __restrict__ out)
{
    __shared__ __align__(16) unsigned short ar[ARENA_U];
    float* fl = (float*)&ar[FLT];

    const int g    = blockIdx.x;
    const int tid  = threadIdx.x;
    const int w    = tid >> 6;      // 0..7
    const int lane = tid & 63;
    const int lm   = lane & 15;
    const int lq   = lane >> 4;

    // A-build ownership: wave 7 -> rows 0..63, wave 6 lanes 0..35 -> rows 64..99
    int arow = -1;
    if (w == 7) arow = lane;
    else if (w == 6 && lane < 36) arow = 64 + lane;
    int er[16];

    // ================= P0: stage everything =================
    {
        // param vectors -> LDS float region
        if (tid < 25)       *(float4*)&fl[FB1 + tid * 4]          = *(const float4*)&b1[tid * 4];
        else if (tid < 30)  *(float4*)&fl[FB2 + (tid - 25) * 4]   = *(const float4*)&b2[(tid - 25) * 4];
        else if (tid < 35)  *(float4*)&fl[FG2 + (tid - 30) * 4]   = *(const float4*)&g2[(tid - 30) * 4];
        else if (tid < 40)  *(float4*)&fl[FBE2 + (tid - 35) * 4]  = *(const float4*)&be2[(tid - 35) * 4];
        else if (tid < 45)  *(float4*)&fl[FG3 + (tid - 40) * 4]   = *(const float4*)&g3[(tid - 40) * 4];
        else if (tid < 50)  *(float4*)&fl[FBE3 + (tid - 45) * 4]  = *(const float4*)&be3[(tid - 45) * 4];
        else if (tid < 100) *(float4*)&fl[FWF1 + (tid - 50) * 4]  = *(const float4*)&Wf1[(tid - 50) * 4];
        else if (tid < 110) { const int j = tid - 100; fl[FBF1 + j] = bf1[j]; fl[FWF2 + j] = Wf2[j]; }
        else if (tid == 110) fl[FBF2] = bf2[0];

        if (arow >= 0) {                                  // edge preload -> regs
            const int* ep = edge_src + g * 1600 + arow * 16;
            int4 e;
            e = *(const int4*)&ep[0];  er[0]=e.x;  er[1]=e.y;  er[2]=e.z;  er[3]=e.w;
            e = *(const int4*)&ep[4];  er[4]=e.x;  er[5]=e.y;  er[6]=e.z;  er[7]=e.w;
            e = *(const int4*)&ep[8];  er[8]=e.x;  er[9]=e.y;  er[10]=e.z; er[11]=e.w;
            e = *(const int4*)&ep[12]; er[12]=e.x; er[13]=e.y; er[14]=e.z; er[15]=e.w;
            const int base = g * 100;
            #pragma unroll
            for (int i = 0; i < 16; ++i) er[i] -= base;
        }

        // feat -> OFF_F bf16 (+ k-pad zero)
        const float* fg = feat + g * 10000;
        for (int i = tid; i < 2500; i += 512) {
            const int n = i / 25, k4 = (i % 25) * 4;
            const float4 v = *(const float4*)&fg[n * 100 + k4];
            *(uint2*)&ar[OFF_F + n * S + k4] = make_uint2(pk2(v.x, v.y), pk2(v.z, v.w));
        }
        for (int i = tid; i < 700; i += 512) {
            const int n = i / 7, j = (i % 7) * 4;
            *(uint2*)&ar[OFF_F + n * S + 100 + j] = make_uint2(0u, 0u);
        }
        // W1 -> OFF_A bf16 (rows 0-99) + k-pad zero
        for (int i = tid; i < 2500; i += 512) {
            const int n = i / 25, k4 = (i % 25) * 4;
            const float4 v = *(const float4*)&W1[n * 100 + k4];
            *(uint2*)&ar[OFF_A + n * S + k4] = make_uint2(pk2(v.x, v.y), pk2(v.z, v.w));
        }
        for (int i = tid; i < 700; i += 512) {
            const int n = i / 7, j = (i % 7) * 4;
            *(uint2*)&ar[OFF_A + n * S + 100 + j] = make_uint2(0u, 0u);
        }
        // W2 -> OFF_S bf16 (rows 0-19) + k-pad zero
        for (int i = tid; i < 500; i += 512) {
            const int n = i / 25, k4 = (i % 25) * 4;
            const float4 v = *(const float4*)&W2[n * 100 + k4];
            *(uint2*)&ar[OFF_S + n * S + k4] = make_uint2(pk2(v.x, v.y), pk2(v.z, v.w));
        }
        for (int i = tid; i < 140; i += 512) {
            const int n = i / 7, j = (i % 7) * 4;
            *(uint2*)&ar[OFF_S + n * S + 100 + j] = make_uint2(0u, 0u);
        }
        // T2t rows 0-19 k-pad zero only (rows 20-31 feed discarded C rows)
        for (int i = tid; i < 140; i += 512) {
            const int n = i / 7, j = (i % 7) * 4;
            *(uint2*)&ar[OFF_T2 + n * S + 100 + j] = make_uint2(0u, 0u);
        }
    }
    __syncthreads();

    // ================= P1: GEMM1 C = feat @ W1^T (waves 0-6); V-dots (wave 7) ====
    f32x4 acc[7];
    {
        const f32x4 z = {0.f, 0.f, 0.f, 0.f};
        #pragma unroll
        for (int n = 0; n < 7; ++n) acc[n] = z;
    }
    if (w < 7) {
        gemm_row<7>(ar, OFF_F, OFF_A, w, lm, lq, acc);
    } else {
        const int j = lane >> 1, h = lane & 1;
        {   // V2[j] = Wv2[j] . self_feat (global reads; pair-split over c)
            const float* wr = Wv2 + j * 200 + h * 100;
            const float* xr = self_feat + g * 200 + h * 100;
            float s = 0.f;
            for (int c = 0; c < 25; ++c) {
                const float4 a = *(const float4*)&wr[c * 4];
                const float4 x = *(const float4*)&xr[c * 4];
                s += a.x * x.x + a.y * x.y + a.z * x.z + a.w * x.w;
            }
            s += __shfl_xor(s, 1);
            if (h == 0) fl[FV2 + j] = s;
        }
        {   // V3[j] = Wv3[j] . x3d (13/12 float4 split)
            const float* wr = Wv3 + j * 100;
            const float* xr = x3d + g * 100;
            const int c0 = h ? 13 : 0, c1 = h ? 25 : 13;
            float s = 0.f;
            for (int c = c0; c < c1; ++c) {
                const float4 a = *(const float4*)&wr[c * 4];
                const float4 x = *(const float4*)&xr[c * 4];
                s += a.x * x.x + a.y * x.y + a.z * x.z + a.w * x.w;
            }
            s += __shfl_xor(s, 1);
            if (h == 0) fl[FV3 + j] = s;
        }
    }
    __syncthreads();

    // ================= P2: T1t epilogue (waves 0-6) + A-build (waves 6,7) ========
    if (w < 7) {
        const int m0 = w * 16 + lq * 4;
        #pragma unroll
        for (int n = 0; n < 7; ++n) {
            const int cc = n * 16 + lm;                   // cc = f1, m0 = node
            if (cc < 100 && m0 <= 96) st4bf(&ar[OFF_F + cc * S + m0], acc[n]);
        }
    }
    if (arow >= 0) {
        const uint4 z4i = make_uint4(0u, 0u, 0u, 0u);
        const int st = (arow >> 3) % 17;                  // conflict groups are row mod 8
        #pragma unroll
        for (int pp = 0; pp < 17; ++pp) {
            int p = pp + st; if (p >= 17) p -= 17;
            *(uint4*)&ar[OFF_A + arow * S + p * 8] = z4i;
        }
        #pragma unroll
        for (int i = 0; i < 16; ++i) {
            int cnt = 0;
            #pragma unroll
            for (int j = 0; j < 16; ++j) cnt += (er[j] == er[i]);
            ar[OFF_A + arow * S + er[i]] = bf16rne((float)cnt * 0.0625f);  // idempotent
        }
    }
    __syncthreads();

    // ================= P3: GEMM2 C2t[f1][dst] = T1t @ A (waves 0-6); Z (wave 7) ==
    {
        const f32x4 z = {0.f, 0.f, 0.f, 0.f};
        #pragma unroll
        for (int n = 0; n < 7; ++n) acc[n] = z;
    }
    if (w < 7) {
        gemm_row<7>(ar, OFF_F, OFF_A, w, lm, lq, acc);
    } else {
        if (lane < 20) {
            const float* wr = Wo2 + lane * 32;
            float s = 0.f;
            #pragma unroll
            for (int c = 0; c < 8; ++c) {
                const float4 a = *(const float4*)&wr[c * 4];
                s += a.x * fl[FV2 + c * 4] + a.y * fl[FV2 + c * 4 + 1]
                   + a.z * fl[FV2 + c * 4 + 2] + a.w * fl[FV2 + c * 4 + 3];
            }
            fl[FZ2 + lane] = s;
        } else if (lane < 40) {
            const int jz = lane - 20;
            const float* wr = Wo3 + jz * 32;
            float s = 0.f;
            #pragma unroll
            for (int c = 0; c < 8; ++c) {
                const float4 a = *(const float4*)&wr[c * 4];
                s += a.x * fl[FV3 + c * 4] + a.y * fl[FV3 + c * 4 + 1]
                   + a.z * fl[FV3 + c * 4 + 2] + a.w * fl[FV3 + c * 4 + 3];
            }
            fl[FZ3 + jz] = s;
        }
    }
    __syncthreads();

    // ================= P4: h1 = relu(C2 + b1) node-major (waves 0-6) =============
    if (w < 7) {
        const int m0 = w * 16 + lq * 4;                   // m0 = f1 base
        if (m0 <= 96) {
            const float4 bb = *(const float4*)&fl[FB1 + m0];
            #pragma unroll
            for (int n = 0; n < 7; ++n) {
                const int cc = n * 16 + lm;               // cc = dst node
                if (cc < 100) {
                    f32x4 v = acc[n];
                    v[0] = fmaxf(v[0] + bb.x, 0.f); v[1] = fmaxf(v[1] + bb.y, 0.f);
                    v[2] = fmaxf(v[2] + bb.z, 0.f); v[3] = fmaxf(v[3] + bb.w, 0.f);
                    st4bf(&ar[OFF_F + cc * S + m0], v);
                }
            }
        }
    }
    __syncthreads();

    // ================= P5: GEMM3 T2t[f2][node] = W2p @ h1 (all 8 waves) ==========
    const int mt  = w & 1;
    const int ntA = w >> 1;            // 0..3
    const bool hasB = (w < 6);
    const int ntB = 4 + (w >> 1);      // 4..6
    {
        const f32x4 z = {0.f, 0.f, 0.f, 0.f};
        f32x4 cA = z, cB = z;
        #pragma unroll
        for (int ks = 0; ks < 4; ++ks) {
            const int k = ks * 32 + lq * 8;
            bf16x8 a = *(const bf16x8*)&ar[OFF_S + (mt * 16 + lm) * S + k];
            bf16x8 bA = *(const bf16x8*)&ar[OFF_F + (ntA * 16 + lm) * S + k];
            cA = __builtin_amdgcn_mfma_f32_16x16x32_bf16(a, bA, cA, 0, 0, 0);
            if (hasB) {
                bf16x8 bB = *(const bf16x8*)&ar[OFF_F + (ntB * 16 + lm) * S + k];
                cB = __builtin_amdgcn_mfma_f32_16x16x32_bf16(a, bB, cB, 0, 0, 0);
            }
        }
        const int ccA = ntA * 16 + lm;
        if (ccA < 100) {
            #pragma unroll
            for (int r = 0; r < 4; ++r) {
                const int f2 = mt * 16 + lq * 4 + r;
                if (f2 < 20) ar[OFF_T2 + f2 * S + ccA] = bf16rne(cA[r]);
            }
        }
        if (hasB) {
            const int ccB = ntB * 16 + lm;
            if (ccB < 100) {
                #pragma unroll
                for (int r = 0; r < 4; ++r) {
                    const int f2 = mt * 16 + lq * 4 + r;
                    if (f2 < 20) ar[OFF_T2 + f2 * S + ccB] = bf16rne(cB[r]);
                }
            }
        }
    }
    __syncthreads();

    // ================= P6: GEMM4 C4t[f2][dst] = T2t @ A; relu+b2 partials ========
    {
        const f32x4 z = {0.f, 0.f, 0.f, 0.f};
        f32x4 cA = z, cB = z;
        #pragma unroll
        for (int ks = 0; ks < 4; ++ks) {
            const int k = ks * 32 + lq * 8;
            bf16x8 a = *(const bf16x8*)&ar[OFF_T2 + (mt * 16 + lm) * S + k];
            bf16x8 bA = *(const bf16x8*)&ar[OFF_A + (ntA * 16 + lm) * S + k];
            cA = __builtin_amdgcn_mfma_f32_16x16x32_bf16(a, bA, cA, 0, 0, 0);
            if (hasB) {
                bf16x8 bB = *(const bf16x8*)&ar[OFF_A + (ntB * 16 + lm) * S + k];
                cB = __builtin_amdgcn_mfma_f32_16x16x32_bf16(a, bB, cB, 0, 0, 0);
            }
        }
        const int ccA = ntA * 16 + lm;
        const int ccB = ntB * 16 + lm;
        #pragma unroll
        for (int r = 0; r < 4; ++r) {
            const int f2 = mt * 16 + lq * 4 + r;
            const bool fv = (f2 < 20);
            const float bias = fv ? fl[FB2 + (fv ? f2 : 0)] : 0.f;
            float val = (fv && ccA < 100) ? fmaxf(cA[r] + bias, 0.f) : 0.f;
            if (hasB && fv && ccB < 100) val += fmaxf(cB[r] + bias, 0.f);
            val += __shfl_xor(val, 1);
            val += __shfl_xor(val, 2);
            val += __shfl_xor(val, 4);
            val += __shfl_xor(val, 8);
            // collision-free partial slot: f2-parity fixes mt=w&1; w>>1 in 0..3
            if (lm == 0 && fv) fl[FHGP + (w >> 1) * 20 + f2] = val;
        }
    }
    __syncthreads();

    // ================= P7: tail on wave 0 (all params in LDS) ====================
    if (tid < 64) {
        const int j = tid;
        float y = 0.f;
        if (j < 20) {
            y = fl[FHGP + j] + fl[FHGP + 20 + j] + fl[FHGP + 40 + j] + fl[FHGP + 60 + j];
            y = y * 0.01f + fl[FZ2 + j];
        }
        float s = y;
        s += __shfl_xor(s, 1); s += __shfl_xor(s, 2); s += __shfl_xor(s, 4);
        s += __shfl_xor(s, 8); s += __shfl_xor(s, 16);
        const float mu = s * 0.05f;
        float d = (j < 20) ? (y - mu) : 0.f;
        float v = d * d;
        v += __shfl_xor(v, 1); v += __shfl_xor(v, 2); v += __shfl_xor(v, 4);
        v += __shfl_xor(v, 8); v += __shfl_xor(v, 16);
        const float inv1 = 1.f / sqrtf(v * 0.05f + LN_EPS);
        float y2 = 0.f;
        if (j < 20) y2 = d * inv1 * fl[FG2 + j] + fl[FBE2 + j] + fl[FZ3 + j];
        float s2 = y2;
        s2 += __shfl_xor(s2, 1); s2 += __shfl_xor(s2, 2); s2 += __shfl_xor(s2, 4);
        s2 += __shfl_xor(s2, 8); s2 += __shfl_xor(s2, 16);
        const float mu2 = s2 * 0.05f;
        float d2 = (j < 20) ? (y2 - mu2) : 0.f;
        float v2 = d2 * d2;
        v2 += __shfl_xor(v2, 1); v2 += __shfl_xor(v2, 2); v2 += __shfl_xor(v2, 4);
        v2 += __shfl_xor(v2, 8); v2 += __shfl_xor(v2, 16);
        const float inv2 = 1.f / sqrtf(v2 * 0.05f + LN_EPS);
        float y3 = 0.f;
        if (j < 20) y3 = d2 * inv2 * fl[FG3 + j] + fl[FBE3 + j];

        // MLP: broadcast shuffles with ALL 64 lanes active (CDNA reads from
        // inactive src lanes return 0 -- R3 lesson).
        float acc7 = 0.f;
        {
            const int js = (j < 10) ? j : 0;
            #pragma unroll
            for (int k = 0; k < 20; ++k) {
                const float yk = __shfl(y3, k);
                acc7 += fl[FWF1 + js * 20 + k] * yk;
            }
            const float bias = fl[FBF1 + js];
            const float w2v  = fl[FWF2 + js];
            acc7 = (j < 10) ? fmaxf(acc7 + bias, 0.f) * w2v : 0.f;
        }
        acc7 += __shfl_xor(acc7, 1); acc7 += __shfl_xor(acc7, 2);
        acc7 += __shfl_xor(acc7, 4); acc7 += __shfl_xor(acc7, 8);
        if (j == 0) out[g] = acc7 + fl[FBF2];
    }
}

extern "C" void kernel_launch(void* const* d_in, const int* in_sizes, int n_in,
                              void* d_out, int out_size, void* d_ws, size_t ws_size,
                              hipStream_t stream) {
    const float* feat      = (const float*)d_in[0];
    const int*   edge_src  = (const int*)  d_in[1];
    // d_in[2] = edge_dst (implicit: node n's edges at n*16..n*16+15)
    const float* self_feat = (const float*)d_in[3];
    const float* x3d       = (const float*)d_in[4];
    const float* W1  = (const float*)d_in[5];
    const float* b1  = (const float*)d_in[6];
    const float* W2  = (const float*)d_in[7];
    const float* b2  = (const float*)d_in[8];
    // d_in[9]=Wq2, d_in[10]=Wk2 unused (length-1 softmax == 1)
    const float* Wv2 = (const float*)d_in[11];
    const float* Wo2 = (const float*)d_in[12];
    const float* g2  = (const float*)d_in[13];
    const float* be2 = (const float*)d_in[14];
    // d_in[15]=Wq3, d_in[16]=Wk3 unused
    const float* Wv3 = (const float*)d_in[17];
    const float* Wo3 = (const float*)d_in[18];
    const float* g3  = (const float*)d_in[19];
    const float* be3 = (const float*)d_in[20];
    const float* Wf1 = (const float*)d_in[21];
    const float* bf1 = (const float*)d_in[22];
    const float* Wf2 = (const float*)d_in[23];
    const float* bf2 = (const float*)d_in[24];

    fused_net_v9<<<512, 512, 0, stream>>>(feat, edge_src, self_feat, x3d,
                                          W1, b1, W2, b2,
                                          Wv2, Wo2, g2, be2,
                                          Wv3, Wo3, g3, be3,
                                          Wf1, bf1, Wf2, bf2,
                                          (float*)d_out);
}

// Round 10
// 129.983 us; speedup vs baseline: 1.0535x; 1.0013x over previous
//
#include <hip/hip_runtime.h>
#include <hip/hip_bf16.h>

#define LN_EPS 1e-5f

typedef __attribute__((ext_vector_type(8))) short bf16x8;
typedef __attribute__((ext_vector_type(4))) float f32x4;

// ---- LDS arena (ushort units). Row stride S=136 (272 B, 16B-aligned;
// bank offset 68 dw == 4 mod 32 -> only free 2-way conflicts). ----
#define S 136
#define OFF_F  0      // feat -> T1t -> h1 (100 rows; spill reads land in A: finite)
#define OFF_A  13600  // W1p (100 rows + 12 spill rows) -> agg A
#define OFF_S  28832  // W2p (32 rows; 20-31 spill -> discarded C rows)
#define OFF_T2 33184  // T2t (rows 0-19 used; 20-31 uninit -> discarded C rows)
#define FLT    37536  // float scratch region
#define ARENA_U 39360 // 78720 B; x2 blocks = 157.4 KB <= 160 KB

// float-region indices
#define FB1  300  // b1 [100]
#define FB2  400  // b2 [20]
#define FG2  420
#define FBE2 440
#define FG3  460
#define FBE3 480
#define FWF1 500  // Wf1 [200]
#define FBF1 700  // bf1 [10] (+pad)
#define FWF2 712  // Wf2 [10] (+pad)
#define FBF2 724  // bf2 [1]  (+pad)
#define FV2  728  // V2 [32]
#define FV3  760  // V3 [32]
#define FZ2  792  // Z2 [20]
#define FZ3  812  // Z3 [20]
#define FHGP 832  // hg partials [4][20] (fully overwritten in P6 -> no init)

__device__ __forceinline__ unsigned short bf16rne(float x) {
    union { float f; unsigned u; } v; v.f = x;
    unsigned r = (v.u + 0x7FFFu + ((v.u >> 16) & 1u)) >> 16;
    return (unsigned short)r;
}

__device__ __forceinline__ unsigned pk2(float a, float b) {
    __hip_bfloat162 h = __float22bfloat162_rn(float2{a, b});
    unsigned r; __builtin_memcpy(&r, &h, 4); return r;
}

__device__ __forceinline__ void st4bf(unsigned short* p, const f32x4 v) {
    *(uint2*)p = make_uint2(pk2(v[0], v[1]), pk2(v[2], v[3]));
}

// K=128 LDS pass, one m-tile row, NT n-tiles. A row-major [m][k]; B as Bt[n][k].
template<int NT>
__device__ __forceinline__ void gemm_row(const unsigned short* __restrict__ ar,
    int Abase, int Bbase, int mrow, int lm, int lq, f32x4 (&acc)[NT])
{
    #pragma unroll
    for (int ks = 0; ks < 4; ++ks) {
        const int k = ks * 32 + lq * 8;
        bf16x8 a = *(const bf16x8*)&ar[Abase + (mrow * 16 + lm) * S + k];
        #pragma unroll
        for (int n = 0; n < NT; ++n) {
            bf16x8 b = *(const bf16x8*)&ar[Bbase + (n * 16 + lm) * S + k];
            acc[n] = __builtin_amdgcn_mfma_f32_16x16x32_bf16(a, b, acc[n], 0, 0, 0);
        }
    }
}

// One block per graph, 512 threads (8 waves): 4 waves/SIMD at 2 blocks/CU.
__global__ __launch_bounds__(512, 4) void fused_net_v10(
    const float* __restrict__ feat, const int* __restrict__ edge_src,
    const float* __restrict__ self_feat, const float* __restrict__ x3d,
    const float* __restrict__ W1, const float* __restrict__ b1,
    const float* __restrict__ W2, const float* __restrict__ b2,
    const float* __restrict__ Wv2, const float* __restrict__ Wo2,
    const float* __restrict__ g2, const float* __restrict__ be2,
    const float* __restrict__ Wv3, const float* __restrict__ Wo3,
    const float* __restrict__ g3, const float* __restrict__ be3,
    const float* __restrict__ Wf1, const float* __restrict__ bf1,
    const float* __restrict__ Wf2, const float* __restrict__ bf2,
    float* __restrict__ out)
{
    __shared__ __align__(16) unsigned short ar[ARENA_U];
    float* fl = (float*)&ar[FLT];

    const int g    = blockIdx.x;
    const int tid  = threadIdx.x;
    const int w    = tid >> 6;      // 0..7
    const int lane = tid & 63;
    const int lm   = lane & 15;
    const int lq   = lane >> 4;

    // A-build ownership: wave 7 -> rows 0..63, wave 6 lanes 0..35 -> rows 64..99
    int arow = -1;
    if (w == 7) arow = lane;
    else if (w == 6 && lane < 36) arow = 64 + lane;
    int er[16];

    // ================= P0: stage everything (batched loads) =================
    {
        // --- issue ALL global loads first: 11 outstanding VMEM per thread.
        //     Indices clamped to last element -> duplicate writes of identical
        //     data (benign) instead of guards, so the unroll can hoist loads.
        float4 vf[5], vw[5], v2;
        int fi[5], wi[5];
        const float* fg = feat + g * 10000;
        #pragma unroll
        for (int it = 0; it < 5; ++it) {
            int i = tid + it * 512; if (i > 2499) i = 2499;
            fi[it] = i;
            vf[it] = *(const float4*)&fg[(i / 25) * 100 + (i % 25) * 4];
        }
        #pragma unroll
        for (int it = 0; it < 5; ++it) {
            int i = tid + it * 512; if (i > 2499) i = 2499;
            wi[it] = i;
            vw[it] = *(const float4*)&W1[(i / 25) * 100 + (i % 25) * 4];
        }
        const int i2 = (tid < 500) ? tid : 499;
        v2 = *(const float4*)&W2[(i2 / 25) * 100 + (i2 % 25) * 4];

        if (arow >= 0) {                                  // edge preload -> regs
            const int* ep = edge_src + g * 1600 + arow * 16;
            int4 e;
            e = *(const int4*)&ep[0];  er[0]=e.x;  er[1]=e.y;  er[2]=e.z;  er[3]=e.w;
            e = *(const int4*)&ep[4];  er[4]=e.x;  er[5]=e.y;  er[6]=e.z;  er[7]=e.w;
            e = *(const int4*)&ep[8];  er[8]=e.x;  er[9]=e.y;  er[10]=e.z; er[11]=e.w;
            e = *(const int4*)&ep[12]; er[12]=e.x; er[13]=e.y; er[14]=e.z; er[15]=e.w;
            const int base = g * 100;
            #pragma unroll
            for (int i = 0; i < 16; ++i) er[i] -= base;
        }

        // param vectors -> LDS float region (low tids)
        if (tid < 25)       *(float4*)&fl[FB1 + tid * 4]          = *(const float4*)&b1[tid * 4];
        else if (tid < 30)  *(float4*)&fl[FB2 + (tid - 25) * 4]   = *(const float4*)&b2[(tid - 25) * 4];
        else if (tid < 35)  *(float4*)&fl[FG2 + (tid - 30) * 4]   = *(const float4*)&g2[(tid - 30) * 4];
        else if (tid < 40)  *(float4*)&fl[FBE2 + (tid - 35) * 4]  = *(const float4*)&be2[(tid - 35) * 4];
        else if (tid < 45)  *(float4*)&fl[FG3 + (tid - 40) * 4]   = *(const float4*)&g3[(tid - 40) * 4];
        else if (tid < 50)  *(float4*)&fl[FBE3 + (tid - 45) * 4]  = *(const float4*)&be3[(tid - 45) * 4];
        else if (tid < 100) *(float4*)&fl[FWF1 + (tid - 50) * 4]  = *(const float4*)&Wf1[(tid - 50) * 4];
        else if (tid < 110) { const int j = tid - 100; fl[FBF1 + j] = bf1[j]; fl[FWF2 + j] = Wf2[j]; }
        else if (tid == 110) fl[FBF2] = bf2[0];

        // k-pad zeros (LDS-only stores; no vmcnt dependence)
        #pragma unroll
        for (int it = 0; it < 2; ++it) {
            const int i = tid + it * 512;
            if (i < 700) {
                const int n = i / 7, j = (i % 7) * 4;
                *(uint2*)&ar[OFF_F + n * S + 100 + j] = make_uint2(0u, 0u);
                *(uint2*)&ar[OFF_A + n * S + 100 + j] = make_uint2(0u, 0u);
            }
        }
        if (tid < 140) {
            const int n = tid / 7, j = (tid % 7) * 4;
            *(uint2*)&ar[OFF_S + n * S + 100 + j]  = make_uint2(0u, 0u);
            *(uint2*)&ar[OFF_T2 + n * S + 100 + j] = make_uint2(0u, 0u);
        }

        // --- convert + LDS stores (loads drain in order) ---
        #pragma unroll
        for (int it = 0; it < 5; ++it) {
            const int n = fi[it] / 25, k4 = (fi[it] % 25) * 4;
            *(uint2*)&ar[OFF_F + n * S + k4] =
                make_uint2(pk2(vf[it].x, vf[it].y), pk2(vf[it].z, vf[it].w));
        }
        #pragma unroll
        for (int it = 0; it < 5; ++it) {
            const int n = wi[it] / 25, k4 = (wi[it] % 25) * 4;
            *(uint2*)&ar[OFF_A + n * S + k4] =
                make_uint2(pk2(vw[it].x, vw[it].y), pk2(vw[it].z, vw[it].w));
        }
        {
            const int n = i2 / 25, k4 = (i2 % 25) * 4;
            *(uint2*)&ar[OFF_S + n * S + k4] =
                make_uint2(pk2(v2.x, v2.y), pk2(v2.z, v2.w));
        }
    }
    __syncthreads();

    // ================= P1: GEMM1 C = feat @ W1^T (waves 0-6); V-dots (wave 7) ====
    f32x4 acc[7];
    {
        const f32x4 z = {0.f, 0.f, 0.f, 0.f};
        #pragma unroll
        for (int n = 0; n < 7; ++n) acc[n] = z;
    }
    if (w < 7) {
        gemm_row<7>(ar, OFF_F, OFF_A, w, lm, lq, acc);
    } else {
        const int j = lane >> 1, h = lane & 1;
        {   // V2[j] = Wv2[j] . self_feat (global reads; pair-split over c)
            const float* wr = Wv2 + j * 200 + h * 100;
            const float* xr = self_feat + g * 200 + h * 100;
            float s = 0.f;
            for (int c = 0; c < 25; ++c) {
                const float4 a = *(const float4*)&wr[c * 4];
                const float4 x = *(const float4*)&xr[c * 4];
                s += a.x * x.x + a.y * x.y + a.z * x.z + a.w * x.w;
            }
            s += __shfl_xor(s, 1);
            if (h == 0) fl[FV2 + j] = s;
        }
        {   // V3[j] = Wv3[j] . x3d (13/12 float4 split)
            const float* wr = Wv3 + j * 100;
            const float* xr = x3d + g * 100;
            const int c0 = h ? 13 : 0, c1 = h ? 25 : 13;
            float s = 0.f;
            for (int c = c0; c < c1; ++c) {
                const float4 a = *(const float4*)&wr[c * 4];
                const float4 x = *(const float4*)&xr[c * 4];
                s += a.x * x.x + a.y * x.y + a.z * x.z + a.w * x.w;
            }
            s += __shfl_xor(s, 1);
            if (h == 0) fl[FV3 + j] = s;
        }
    }
    __syncthreads();

    // ================= P2: T1t epilogue (waves 0-6) + A-build (waves 6,7) ========
    if (w < 7) {
        const int m0 = w * 16 + lq * 4;
        #pragma unroll
        for (int n = 0; n < 7; ++n) {
            const int cc = n * 16 + lm;                   // cc = f1, m0 = node
            if (cc < 100 && m0 <= 96) st4bf(&ar[OFF_F + cc * S + m0], acc[n]);
        }
    }
    if (arow >= 0) {
        const uint4 z4i = make_uint4(0u, 0u, 0u, 0u);
        const int st = (arow >> 3) % 17;                  // conflict groups are row mod 8
        #pragma unroll
        for (int pp = 0; pp < 17; ++pp) {
            int p = pp + st; if (p >= 17) p -= 17;
            *(uint4*)&ar[OFF_A + arow * S + p * 8] = z4i;
        }
        #pragma unroll
        for (int i = 0; i < 16; ++i) {
            int cnt = 0;
            #pragma unroll
            for (int j = 0; j < 16; ++j) cnt += (er[j] == er[i]);
            ar[OFF_A + arow * S + er[i]] = bf16rne((float)cnt * 0.0625f);  // idempotent
        }
    }
    __syncthreads();

    // ================= P3: GEMM2 C2t[f1][dst] = T1t @ A (waves 0-6); Z (wave 7) ==
    {
        const f32x4 z = {0.f, 0.f, 0.f, 0.f};
        #pragma unroll
        for (int n = 0; n < 7; ++n) acc[n] = z;
    }
    if (w < 7) {
        gemm_row<7>(ar, OFF_F, OFF_A, w, lm, lq, acc);
    } else {
        if (lane < 20) {
            const float* wr = Wo2 + lane * 32;
            float s = 0.f;
            #pragma unroll
            for (int c = 0; c < 8; ++c) {
                const float4 a = *(const float4*)&wr[c * 4];
                s += a.x * fl[FV2 + c * 4] + a.y * fl[FV2 + c * 4 + 1]
                   + a.z * fl[FV2 + c * 4 + 2] + a.w * fl[FV2 + c * 4 + 3];
            }
            fl[FZ2 + lane] = s;
        } else if (lane < 40) {
            const int jz = lane - 20;
            const float* wr = Wo3 + jz * 32;
            float s = 0.f;
            #pragma unroll
            for (int c = 0; c < 8; ++c) {
                const float4 a = *(const float4*)&wr[c * 4];
                s += a.x * fl[FV3 + c * 4] + a.y * fl[FV3 + c * 4 + 1]
                   + a.z * fl[FV3 + c * 4 + 2] + a.w * fl[FV3 + c * 4 + 3];
            }
            fl[FZ3 + jz] = s;
        }
    }
    __syncthreads();

    // ================= P4: h1 = relu(C2 + b1) node-major (waves 0-6) =============
    if (w < 7) {
        const int m0 = w * 16 + lq * 4;                   // m0 = f1 base
        if (m0 <= 96) {
            const float4 bb = *(const float4*)&fl[FB1 + m0];
            #pragma unroll
            for (int n = 0; n < 7; ++n) {
                const int cc = n * 16 + lm;               // cc = dst node
                if (cc < 100) {
                    f32x4 v = acc[n];
                    v[0] = fmaxf(v[0] + bb.x, 0.f); v[1] = fmaxf(v[1] + bb.y, 0.f);
                    v[2] = fmaxf(v[2] + bb.z, 0.f); v[3] = fmaxf(v[3] + bb.w, 0.f);
                    st4bf(&ar[OFF_F + cc * S + m0], v);
                }
            }
        }
    }
    __syncthreads();

    // ================= P5: GEMM3 T2t[f2][node] = W2p @ h1 (all 8 waves) ==========
    const int mt  = w & 1;
    const int ntA = w >> 1;            // 0..3
    const bool hasB = (w < 6);
    const int ntB = 4 + (w >> 1);      // 4..6
    {
        const f32x4 z = {0.f, 0.f, 0.f, 0.f};
        f32x4 cA = z, cB = z;
        #pragma unroll
        for (int ks = 0; ks < 4; ++ks) {
            const int k = ks * 32 + lq * 8;
            bf16x8 a = *(const bf16x8*)&ar[OFF_S + (mt * 16 + lm) * S + k];
            bf16x8 bA = *(const bf16x8*)&ar[OFF_F + (ntA * 16 + lm) * S + k];
            cA = __builtin_amdgcn_mfma_f32_16x16x32_bf16(a, bA, cA, 0, 0, 0);
            if (hasB) {
                bf16x8 bB = *(const bf16x8*)&ar[OFF_F + (ntB * 16 + lm) * S + k];
                cB = __builtin_amdgcn_mfma_f32_16x16x32_bf16(a, bB, cB, 0, 0, 0);
            }
        }
        const int ccA = ntA * 16 + lm;
        if (ccA < 100) {
            #pragma unroll
            for (int r = 0; r < 4; ++r) {
                const int f2 = mt * 16 + lq * 4 + r;
                if (f2 < 20) ar[OFF_T2 + f2 * S + ccA] = bf16rne(cA[r]);
            }
        }
        if (hasB) {
            const int ccB = ntB * 16 + lm;
            if (ccB < 100) {
                #pragma unroll
                for (int r = 0; r < 4; ++r) {
                    const int f2 = mt * 16 + lq * 4 + r;
                    if (f2 < 20) ar[OFF_T2 + f2 * S + ccB] = bf16rne(cB[r]);
                }
            }
        }
    }
    __syncthreads();

    // ================= P6: GEMM4 C4t[f2][dst] = T2t @ A; relu+b2 partials ========
    {
        const f32x4 z = {0.f, 0.f, 0.f, 0.f};
        f32x4 cA = z, cB = z;
        #pragma unroll
        for (int ks = 0; ks < 4; ++ks) {
            const int k = ks * 32 + lq * 8;
            bf16x8 a = *(const bf16x8*)&ar[OFF_T2 + (mt * 16 + lm) * S + k];
            bf16x8 bA = *(const bf16x8*)&ar[OFF_A + (ntA * 16 + lm) * S + k];
            cA = __builtin_amdgcn_mfma_f32_16x16x32_bf16(a, bA, cA, 0, 0, 0);
            if (hasB) {
                bf16x8 bB = *(const bf16x8*)&ar[OFF_A + (ntB * 16 + lm) * S + k];
                cB = __builtin_amdgcn_mfma_f32_16x16x32_bf16(a, bB, cB, 0, 0, 0);
            }
        }
        const int ccA = ntA * 16 + lm;
        const int ccB = ntB * 16 + lm;
        #pragma unroll
        for (int r = 0; r < 4; ++r) {
            const int f2 = mt * 16 + lq * 4 + r;
            const bool fv = (f2 < 20);
            const float bias = fv ? fl[FB2 + (fv ? f2 : 0)] : 0.f;
            float val = (fv && ccA < 100) ? fmaxf(cA[r] + bias, 0.f) : 0.f;
            if (hasB && fv && ccB < 100) val += fmaxf(cB[r] + bias, 0.f);
            val += __shfl_xor(val, 1);
            val += __shfl_xor(val, 2);
            val += __shfl_xor(val, 4);
            val += __shfl_xor(val, 8);
            // collision-free partial slot: f2-parity fixes mt=w&1; w>>1 in 0..3
            if (lm == 0 && fv) fl[FHGP + (w >> 1) * 20 + f2] = val;
        }
    }
    __syncthreads();

    // ================= P7: tail on wave 0 (all params in LDS) ====================
    if (tid < 64) {
        const int j = tid;
        float y = 0.f;
        if (j < 20) {
            y = fl[FHGP + j] + fl[FHGP + 20 + j] + fl[FHGP + 40 + j] + fl[FHGP + 60 + j];
            y = y * 0.01f + fl[FZ2 + j];
        }
        float s = y;
        s += __shfl_xor(s, 1); s += __shfl_xor(s, 2); s += __shfl_xor(s, 4);
        s += __shfl_xor(s, 8); s += __shfl_xor(s, 16);
        const float mu = s * 0.05f;
        float d = (j < 20) ? (y - mu) : 0.f;
        float v = d * d;
        v += __shfl_xor(v, 1); v += __shfl_xor(v, 2); v += __shfl_xor(v, 4);
        v += __shfl_xor(v, 8); v += __shfl_xor(v, 16);
        const float inv1 = 1.f / sqrtf(v * 0.05f + LN_EPS);
        float y2 = 0.f;
        if (j < 20) y2 = d * inv1 * fl[FG2 + j] + fl[FBE2 + j] + fl[FZ3 + j];
        float s2 = y2;
        s2 += __shfl_xor(s2, 1); s2 += __shfl_xor(s2, 2); s2 += __shfl_xor(s2, 4);
        s2 += __shfl_xor(s2, 8); s2 += __shfl_xor(s2, 16);
        const float mu2 = s2 * 0.05f;
        float d2 = (j < 20) ? (y2 - mu2) : 0.f;
        float v2 = d2 * d2;
        v2 += __shfl_xor(v2, 1); v2 += __shfl_xor(v2, 2); v2 += __shfl_xor(v2, 4);
        v2 += __shfl_xor(v2, 8); v2 += __shfl_xor(v2, 16);
        const float inv2 = 1.f / sqrtf(v2 * 0.05f + LN_EPS);
        float y3 = 0.f;
        if (j < 20) y3 = d2 * inv2 * fl[FG3 + j] + fl[FBE3 + j];

        // MLP: broadcast shuffles with ALL 64 lanes active (CDNA reads from
        // inactive src lanes return 0 -- R3 lesson).
        float acc7 = 0.f;
        {
            const int js = (j < 10) ? j : 0;
            #pragma unroll
            for (int k = 0; k < 20; ++k) {
                const float yk = __shfl(y3, k);
                acc7 += fl[FWF1 + js * 20 + k] * yk;
            }
            const float bias = fl[FBF1 + js];
            const float w2v  = fl[FWF2 + js];
            acc7 = (j < 10) ? fmaxf(acc7 + bias, 0.f) * w2v : 0.f;
        }
        acc7 += __shfl_xor(acc7, 1); acc7 += __shfl_xor(acc7, 2);
        acc7 += __shfl_xor(acc7, 4); acc7 += __shfl_xor(acc7, 8);
        if (j == 0) out[g] = acc7 + fl[FBF2];
    }
}

extern "C" void kernel_launch(void* const* d_in, const int* in_sizes, int n_in,
                              void* d_out, int out_size, void* d_ws, size_t ws_size,
                              hipStream_t stream) {
    const float* feat      = (const float*)d_in[0];
    const int*   edge_src  = (const int*)  d_in[1];
    // d_in[2] = edge_dst (implicit: node n's edges at n*16..n*16+15)
    const float* self_feat = (const float*)d_in[3];
    const float* x3d       = (const float*)d_in[4];
    const float* W1  = (const float*)d_in[5];
    const float* b1  = (const float*)d_in[6];
    const float* W2  = (const float*)d_in[7];
    const float* b2  = (const float*)d_in[8];
    // d_in[9]=Wq2, d_in[10]=Wk2 unused (length-1 softmax == 1)
    const float* Wv2 = (const float*)d_in[11];
    const float* Wo2 = (const float*)d_in[12];
    const float* g2  = (const float*)d_in[13];
    const float* be2 = (const float*)d_in[14];
    // d_in[15]=Wq3, d_in[16]=Wk3 unused
    const float* Wv3 = (const float*)d_in[17];
    const float* Wo3 = (const float*)d_in[18];
    const float* g3  = (const float*)d_in[19];
    const float* be3 = (const float*)d_in[20];
    const float* Wf1 = (const float*)d_in[21];
    const float* bf1 = (const float*)d_in[22];
    const float* Wf2 = (const float*)d_in[23];
    const float* bf2 = (const float*)d_in[24];

    fused_net_v10<<<512, 512, 0, stream>>>(feat, edge_src, self_feat, x3d,
                                           W1, b1, W2, b2,
                                           Wv2, Wo2, g2, be2,
                                           Wv3, Wo3, g3, be3,
                                           Wf1, bf1, Wf2, bf2,
                                           (float*)d_out);
}